// Round 2
// baseline (9743.050 us; speedup 1.0000x reference)
//
#include <hip/hip_runtime.h>
#include <hip/hip_bf16.h>
#include <cstdint>
#include <cstddef>

#define DEV __device__ __forceinline__

typedef _Float16 h2v __attribute__((ext_vector_type(2)));
typedef unsigned u4v __attribute__((ext_vector_type(4)));

DEV float sigmoidf_(float x) { return 1.0f / (1.0f + __expf(-x)); }
DEV float tanhf_(float x) {
    float e = __expf(2.0f * x);
    return 1.0f - 2.0f / (e + 1.0f);
}
DEV h2v asH2(unsigned x) { union { unsigned u; h2v h; } c; c.u = x; return c.h; }

// Un-sinkable, un-rematerializable 16B load (resident weights).
DEV u4v gload(const void* p) {
    u4v r;
    asm volatile("global_load_dwordx4 %0, %1, off\n\ts_waitcnt vmcnt(0)"
                 : "=v"(r) : "v"(p) : "memory");
    return r;
}

// LDS-only barrier: does NOT drain vmcnt; global prefetch/stores stay in flight.
#define LDS_BARRIER() asm volatile("s_waitcnt lgkmcnt(0)\n\ts_barrier" ::: "memory")

// ---------------------------------------------------------------------------
// Pack 10 matrices (256x64 each) to f16 pairs, split-K layout:
//   dst[m][half][qs][u][w]   (qs = q*4+s: gate q, slice s; w = word 0..3)
// m: 0-2 l1Whh, 3-5 l2Whh, 6-7 Wih12 (l1 layers 1,2), 8-9 l2Wih layers 1,2.
// Quad (half,q,s,u) holds W[gate q][unit u][k = 32*half + 8*s .. +7].
// ---------------------------------------------------------------------------
__global__ __launch_bounds__(256) void pack_w(
    const float* __restrict__ l1Whh, const float* __restrict__ l2Whh,
    const float* __restrict__ Wih12, const float* __restrict__ l2Wih,
    unsigned* __restrict__ wP)
{
    int idx = blockIdx.x * 256 + threadIdx.x;   // 10*8192 = 81920
    int m = idx >> 13;
    int rem = idx & 8191;
    int half = rem >> 12;
    int qs = (rem >> 8) & 15;
    int u = (rem >> 2) & 63;
    int w = rem & 3;
    int q = qs >> 2, s = qs & 3;
    int jp = 16 * half + 4 * s + w;

    const float* W;
    if (m < 3)      W = l1Whh + (size_t)m * 16384;
    else if (m < 6) W = l2Whh + (size_t)(m - 3) * 16384;
    else if (m < 8) W = Wih12 + (size_t)(m - 6) * 16384;
    else            W = l2Wih + (size_t)(m - 7) * 16384;   // layers 1,2

    const float* row = W + (size_t)(q * 64 + u) * 64;
    union { h2v h; unsigned u32; } c;
    c.h = (h2v){(_Float16)row[2 * jp], (_Float16)row[2 * jp + 1]};
    wP[idx] = c.u32;
}

// ---------------------------------------------------------------------------
// Input projection (layer 0 of each stack only): xg[b,t,u*4+q] unit-major.
// ---------------------------------------------------------------------------
__global__ __launch_bounds__(256) void proj_kernel(
    const float* __restrict__ x, const float* __restrict__ Wih,
    const float* __restrict__ bias, const float* __restrict__ gate,
    float* __restrict__ xg, int D, int T)
{
    __shared__ float xS[16 * 64];
    int tb = T / 16;
    int b  = blockIdx.x / tb;
    int t0 = (blockIdx.x % tb) * 16;
    int tid = threadIdx.x;

    int n = 16 * D;
    for (int e = tid; e < n; e += 256) {
        int t = e / D;
        int i = e - t * D;
        float v = x[((size_t)(b * T + t0 + t)) * D + i];
        if (gate) v += gate[b * T + t0 + t];
        xS[t * D + i] = v;
    }
    __syncthreads();

    int g = tid;
    float acc[16];
    float bg = bias[g];
#pragma unroll
    for (int t = 0; t < 16; t++) acc[t] = bg;

    const float* wr = Wih + (size_t)g * D;
    for (int i = 0; i < D; i++) {
        float w = wr[i];
#pragma unroll
        for (int t = 0; t < 16; t++) acc[t] += xS[t * D + i] * w;
    }

    float* og = xg + ((size_t)(b * T + t0)) * 256 + (g & 63) * 4 + (g >> 6);
#pragma unroll
    for (int t = 0; t < 16; t++) og[(size_t)t * 256] = acc[t];
}

// ---------------------------------------------------------------------------
// Chunked 3-layer LSTM scan v17: ONE block per batch, THREE waves (1/layer).
//
// v15/v16 both plateaued at ~2300 cyc/tick despite opposite register
// strategies -> the cost is the per-tick lockstep (barrier + simultaneous
// LDS burst + convoy), not spills. v17 decouples the waves:
//  * Epochs of R=8 ticks; ONE barrier per epoch. Within an epoch each wave
//    is self-contained: own-h broadcast via private hself row (same-wave
//    in-order LDS, no sync); h from layer below via hchunk buffers written
//    a full epoch earlier (epoch-parity double buffer -> race-free).
//  * Lane = unit (full K=64): no cross-lane reduce, one act per unit.
//  * ALL weights in LDS (153.6KB); the 5-slice tail of each Wih lives in
//    20 VGPRs (rw0..4) to fit the 160KB LDS cap. Zero per-tick global
//    weight traffic, zero spill (demand ~100 vs 3-wave grant).
//  * Wih.h_below partial for tick t+1 computed at END of tick t (h_below
//    is already known) -> hides the own-h LDS round-trip behind 256
//    issue cycles. Epoch head computes the partial for r=0.
//  * L0: 4-deep rolling global x prefetch (slot tau mod 4 invariant).
// ---------------------------------------------------------------------------
#define RR 8

__global__
__attribute__((amdgpu_flat_work_group_size(192, 192), amdgpu_waves_per_eu(1, 1)))
void scan3_kernel(
    const float* __restrict__ xg, const unsigned* __restrict__ whhP,
    const unsigned* __restrict__ wihP, const float* __restrict__ bvec,
    const float* __restrict__ h0, const float* __restrict__ c0,
    float* __restrict__ Hout, int T)
{
    // wS (u4v units): whh0 @0, whh1 @2048, whh2 @4096 (full 2048 each)
    //                 wih1 @6144, wih2 @7872 (truncated: 1728 each)
    __shared__ __align__(16) u4v wS[9600];                 // 153600 B
    __shared__ __align__(16) _Float16 hchunk[2][2][RR][64]; // 4096 B
    __shared__ __align__(16) _Float16 hself[3][64];         // 384 B

    const int b = blockIdx.x, tid = threadIdx.x;
    const int l = tid >> 6, u = tid & 63;

    // ---- stage weights into LDS ----
    {
        const u4v* wg = (const u4v*)whhP;
        for (int i = tid; i < 6144; i += 192) wS[i] = wg[i];
        const u4v* wx = (const u4v*)wihP;
        for (int i = tid; i < 1728; i += 192) wS[6144 + i] = wx[i];
        for (int i = tid; i < 1728; i += 192) wS[7872 + i] = wx[2048 + i];
    }
    // resident Wih tail (5 slices: qs=11..15, half=1) for l in {1,2}
    u4v rw0 = {0,0,0,0}, rw1 = rw0, rw2 = rw0, rw3 = rw0, rw4 = rw0;
    if (l > 0) {
        const u4v* wt = (const u4v*)wihP + (size_t)(l - 1) * 2048 + 1728 + u;
        rw0 = gload(wt + 0 * 64); rw1 = gload(wt + 1 * 64);
        rw2 = gload(wt + 2 * 64); rw3 = gload(wt + 3 * 64);
        rw4 = gload(wt + 4 * 64);
    }

    float cst = c0[l * 128 + b * 64 + u];
    hself[l][u] = (_Float16)h0[l * 128 + b * 64 + u];
    float4 bl = make_float4(0.f, 0.f, 0.f, 0.f);
    if (l > 0) {
        const float* bb = bvec + l * 256;
        bl = make_float4(bb[u], bb[64 + u], bb[128 + u], bb[192 + u]);
    }

    const float4* xp = (const float4*)(xg + (size_t)b * T * 256) + u;
    float4 z4 = make_float4(0.f, 0.f, 0.f, 0.f);
    float4 xb0 = z4, xb1 = z4, xb2 = z4, xb3 = z4;
    if (l == 0) { xb0 = xp[0]; xb1 = xp[64]; xb2 = xp[128]; xb3 = xp[192]; }

    float* houtp = Hout + (size_t)b * T * 64 + u;
    const u4v* hs = (const u4v*)&hself[l][0];
    const int whhB = l * 2048;
    const int wihB = 6144 + (l > 0 ? (l - 1) : 0) * 1728;

    __syncthreads();

#define FD(HP, WV, A) A = __builtin_amdgcn_fdot2(asH2(HP), asH2(WV), A, false)
#define DOTQ(HQ, WQ, A) { u4v wq_ = (WQ); \
    FD(HQ.x, wq_.x, A); FD(HQ.y, wq_.y, A); FD(HQ.z, wq_.z, A); FD(HQ.w, wq_.w, A); }

    // Whh quad (gate G, h-quad J) for this wave, from LDS:
#define WHHQ(G, J) wS[whhB + ((J) >> 2) * 1024 + ((G) * 4 + ((J) & 3)) * 64 + u]
#define WHHJ(J, HJ) { DOTQ(HJ, WHHQ(0, J), aI); DOTQ(HJ, WHHQ(1, J), aF); \
                      DOTQ(HJ, WHHQ(2, J), aG); DOTQ(HJ, WHHQ(3, J), aO); }

    // Wih quad: LDS except resident tail (folds at compile time: J,G const)
#define WIHQL(G, J) wS[wihB + ((J) >> 2) * 1024 + ((G) * 4 + ((J) & 3)) * 64 + u]
#define WIHG2(J) (((J) == 7) ? rw0 : WIHQL(2, J))
#define WIHG3(J) (((J) == 4) ? rw1 : ((J) == 5) ? rw2 : ((J) == 6) ? rw3 : \
                  ((J) == 7) ? rw4 : WIHQL(3, J))
#define WIHJ(J) { u4v hq_ = hb_[J]; \
    DOTQ(hq_, WIHQL(0, J), nI); DOTQ(hq_, WIHQL(1, J), nF); \
    DOTQ(hq_, WIHG2(J), nG);    DOTQ(hq_, WIHG3(J), nO); }

#define WIH_PHASE(HBP) { const u4v* hb_ = (HBP); \
    WIHJ(0) WIHJ(1) WIHJ(2) WIHJ(3) WIHJ(4) WIHJ(5) WIHJ(6) WIHJ(7) }

#define WHH_PHASE() { WHHJ(0, h0q) WHHJ(1, h1q) WHHJ(2, h2q) WHHJ(3, h3q) \
                      WHHJ(4, h4q) WHHJ(5, h5q) WHHJ(6, h6q) WHHJ(7, h7q) }

#define ACT_WRITE(TAU, RSLOT) { \
    cst = sigmoidf_(aF) * cst + sigmoidf_(aI) * tanhf_(aG); \
    float hv = sigmoidf_(aO) * tanhf_(cst); \
    _Float16 h16 = (_Float16)hv; \
    hself[l][u] = h16; \
    if (l < 2) hchunk[l][p][RSLOT][u] = h16; \
    else houtp[(size_t)(TAU) * 64] = hv; }

#define HQ_RELOAD() { h0q = hs[0]; h1q = hs[1]; h2q = hs[2]; h3q = hs[3]; \
                      h4q = hs[4]; h5q = hs[5]; h6q = hs[6]; h7q = hs[7]; }

    // x-prefetch slot: tick tau lives in slot tau&3 (base % 4 == 0 always)
#define XBSLOT(S) (((S) & 3) == 0 ? xb0 : ((S) & 3) == 1 ? xb1 : \
                   ((S) & 3) == 2 ? xb2 : xb3)

    const int NC = T / RR;
    float4 acc = z4;
    u4v h0q = {0,0,0,0}, h1q = h0q, h2q = h0q, h3q = h0q;
    u4v h4q = h0q, h5q = h0q, h6q = h0q, h7q = h0q;
    float aI, aF, aG, aO;

    for (int e = 0; e < NC + 2; e++) {
        int m = e - l;
        if (m >= 0 && m < NC) {
            const int p = m & 1;
            const int base = m * RR;
            if (m == 0) HQ_RELOAD();            // h(-1) = h0

            if (l == 0) {
                if (m == 0) { acc = xb0; xb0 = xp[(size_t)4 * 64]; }
#pragma unroll 4
                for (int r = 0; r < RR; r++) {
                    int tau = base + r;
                    aI = acc.x; aF = acc.y; aG = acc.z; aO = acc.w;
                    WHH_PHASE();
                    ACT_WRITE(tau, r);
                    HQ_RELOAD();                // for tick tau+1 (issued early)
                    acc = XBSLOT(r + 1);        // preact for tau+1
                    int tp = tau + 5; if (tp > T - 1) tp = T - 1;
                    XBSLOT(r + 1) = xp[(size_t)tp * 64];
                }
            } else {
                // epoch head: Wih partial + bias for tick r=0 of this chunk
                {
                    float nI = bl.x, nF = bl.y, nG = bl.z, nO = bl.w;
                    WIH_PHASE((const u4v*)&hchunk[l - 1][p][0][0]);
                    acc = make_float4(nI, nF, nG, nO);
                }
#pragma unroll 2
                for (int r = 0; r < RR; r++) {
                    int tau = base + r;
                    aI = acc.x; aF = acc.y; aG = acc.z; aO = acc.w;
                    WHH_PHASE();
                    ACT_WRITE(tau, r);
                    HQ_RELOAD();                // own h for tau+1, issued early
                    if (r < RR - 1) {           // Wih partial for tau+1
                        float nI = bl.x, nF = bl.y, nG = bl.z, nO = bl.w;
                        WIH_PHASE((const u4v*)&hchunk[l - 1][p][r + 1][0]);
                        acc = make_float4(nI, nF, nG, nO);
                    }
                }
            }
        }
        LDS_BARRIER();   // epoch boundary: hchunk writes become visible
    }
#undef FD
#undef DOTQ
#undef WHHQ
#undef WHHJ
#undef WIHQL
#undef WIHG2
#undef WIHG3
#undef WIHJ
#undef WIH_PHASE
#undef WHH_PHASE
#undef ACT_WRITE
#undef HQ_RELOAD
#undef XBSLOT
}

// ---------------------------------------------------------------------------
// Hc[b, {max,mean,std(ddof=1)}, t] over hidden dim (64). One wave per (b,t).
// ---------------------------------------------------------------------------
__global__ __launch_bounds__(256) void stats_kernel(
    const float* __restrict__ H, float* __restrict__ Hc, int T)
{
    int wid = threadIdx.x >> 6, lane = threadIdx.x & 63;
    int bt = blockIdx.x * 4 + wid;
    int b = bt / T, t = bt - b * T;

    float x = H[(size_t)bt * 64 + lane];
    float mx = x, sm = x;
#pragma unroll
    for (int m = 32; m >= 1; m >>= 1) {
        mx = fmaxf(mx, __shfl_xor(mx, m));
        sm += __shfl_xor(sm, m);
    }
    float mean = sm * (1.0f / 64.0f);
    float d = x - mean;
    float ss = d * d;
#pragma unroll
    for (int m = 32; m >= 1; m >>= 1) ss += __shfl_xor(ss, m);
    float sd = sqrtf(ss * (1.0f / 63.0f));

    if (lane == 0) {
        float* o = Hc + (size_t)b * 3 * T;
        o[0 * T + t] = mx;
        o[1 * T + t] = mean;
        o[2 * T + t] = sd;
    }
}

// ---------------------------------------------------------------------------
// Middle conv/BN chain, single workgroup (1024 threads).
// ---------------------------------------------------------------------------
template <int CIN, int COUT, int MODE>
DEV void conv_bn_stage(const float* __restrict__ in, const float* __restrict__ w,
                       const float* __restrict__ bias, float* __restrict__ out,
                       float* __restrict__ gate, int T, int tid,
                       float* rs, float* rq, float* stm, float* sti)
{
    float lsum[COUT], lss[COUT];
#pragma unroll
    for (int oc = 0; oc < COUT; oc++) { lsum[oc] = 0.f; lss[oc] = 0.f; }

    for (int k = 0; k < 8; k++) {
        int p = tid + k * 1024;
        int b = p / T;
        int t = p - b * T;
        float acc[COUT];
#pragma unroll
        for (int oc = 0; oc < COUT; oc++) acc[oc] = bias[oc];
#pragma unroll
        for (int ic = 0; ic < CIN; ic++) {
            const float* row = in + ((size_t)b * CIN + ic) * T;
            float xv[11];
#pragma unroll
            for (int kk = 0; kk < 11; kk++) {
                int tt = t + kk - 5;
                xv[kk] = (tt >= 0 && tt < T) ? row[tt] : 0.f;
            }
#pragma unroll
            for (int oc = 0; oc < COUT; oc++) {
                const float* wr = w + ((size_t)oc * CIN + ic) * 11;
#pragma unroll
                for (int kk = 0; kk < 11; kk++) acc[oc] += xv[kk] * wr[kk];
            }
        }
#pragma unroll
        for (int oc = 0; oc < COUT; oc++) {
            out[((size_t)b * COUT + oc) * T + t] = acc[oc];
            lsum[oc] += acc[oc];
            lss[oc] += acc[oc] * acc[oc];
        }
    }
    __syncthreads();

    int lane = tid & 63, wid = tid >> 6;
#pragma unroll
    for (int oc = 0; oc < COUT; oc++) {
        float s = lsum[oc], qq = lss[oc];
#pragma unroll
        for (int m = 32; m >= 1; m >>= 1) {
            s += __shfl_xor(s, m);
            qq += __shfl_xor(qq, m);
        }
        if (lane == 0) { rs[wid] = s; rq[wid] = qq; }
        __syncthreads();
        if (tid == 0) {
            float S = 0.f, Q = 0.f;
            for (int i = 0; i < 16; i++) { S += rs[i]; Q += rq[i]; }
            float m_ = S / (float)(2 * T);
            float v = Q / (float)(2 * T) - m_ * m_;
            stm[oc] = m_;
            sti[oc] = rsqrtf(v + 1e-5f);
        }
        __syncthreads();
    }

    for (int k = 0; k < 8; k++) {
        int p = tid + k * 1024;
        int b = p / T;
        int t = p - b * T;
#pragma unroll
        for (int oc = 0; oc < COUT; oc++) {
            size_t idx = ((size_t)b * COUT + oc) * T + t;
            float v = (out[idx] - stm[oc]) * sti[oc];
            if (MODE == 0) out[idx] = fmaxf(v, 0.f);
            else           gate[p] = sigmoidf_(v);
        }
    }
    __syncthreads();
}

__global__ __launch_bounds__(1024) void middle_kernel(
    const float* __restrict__ Hc,
    const float* __restrict__ w1, const float* __restrict__ b1,
    const float* __restrict__ w2, const float* __restrict__ b2,
    const float* __restrict__ w3, const float* __restrict__ b3,
    const float* __restrict__ w4, const float* __restrict__ b4,
    float* __restrict__ bufA, float* __restrict__ bufB,
    float* __restrict__ gate, int T)
{
    __shared__ float rs[16], rq[16], stm[8], sti[8];
    int tid = threadIdx.x;
    conv_bn_stage<3, 3, 0>(Hc,   w1, b1, bufA, nullptr, T, tid, rs, rq, stm, sti);
    conv_bn_stage<3, 5, 0>(bufA, w2, b2, bufB, nullptr, T, tid, rs, rq, stm, sti);
    conv_bn_stage<5, 5, 0>(bufB, w3, b3, bufA, nullptr, T, tid, rs, rq, stm, sti);
    conv_bn_stage<5, 1, 1>(bufA, w4, b4, bufB, gate,    T, tid, rs, rq, stm, sti);
}

// ---------------------------------------------------------------------------
// Head: y = sigmoid(fc2(fc1(out2))). One wave per (b,t).
// ---------------------------------------------------------------------------
__global__ __launch_bounds__(256) void final_kernel(
    const float* __restrict__ out2, const float* __restrict__ fc1w,
    const float* __restrict__ fc1b, const float* __restrict__ fc2w,
    const float* __restrict__ fc2b, float* __restrict__ out, int T)
{
    int wid = threadIdx.x >> 6, lane = threadIdx.x & 63;
    int bt = blockIdx.x * 4 + wid;

    const float* o2 = out2 + (size_t)bt * 64;
    float acc = fc1b[lane];
    const float* wr = fc1w + (size_t)lane * 64;
#pragma unroll
    for (int k = 0; k < 64; k++) acc += o2[k] * wr[k];

    float p = acc * fc2w[lane];
#pragma unroll
    for (int m = 32; m >= 1; m >>= 1) p += __shfl_xor(p, m);

    if (lane == 0) out[bt] = sigmoidf_(p + fc2b[0]);
}

// ---------------------------------------------------------------------------
extern "C" void kernel_launch(void* const* d_in, const int* in_sizes, int n_in,
                              void* d_out, int out_size, void* d_ws, size_t ws_size,
                              hipStream_t stream)
{
    const float* data  = (const float*)d_in[0];
    const float* h01   = (const float*)d_in[1];
    const float* c01   = (const float*)d_in[2];
    const float* h02   = (const float*)d_in[3];
    const float* c02   = (const float*)d_in[4];
    const float* Wih0  = (const float*)d_in[5];
    const float* Wih12 = (const float*)d_in[6];
    const float* l1Whh = (const float*)d_in[7];
    const float* l1b   = (const float*)d_in[8];
    const float* l2Wih = (const float*)d_in[9];
    const float* l2Whh = (const float*)d_in[10];
    const float* l2b   = (const float*)d_in[11];
    const float* cw1 = (const float*)d_in[12]; const float* cb1 = (const float*)d_in[13];
    const float* cw2 = (const float*)d_in[14]; const float* cb2 = (const float*)d_in[15];
    const float* cw3 = (const float*)d_in[16]; const float* cb3 = (const float*)d_in[17];
    const float* cw4 = (const float*)d_in[18]; const float* cb4 = (const float*)d_in[19];
    const float* fc1w = (const float*)d_in[20]; const float* fc1b = (const float*)d_in[21];
    const float* fc2w = (const float*)d_in[22]; const float* fc2b = (const float*)d_in[23];
    float* out = (float*)d_out;

    const int T = in_sizes[0] / (2 * 40);   // 4096
    const int B = 2;

    float* ws   = (float*)d_ws;
    float* xg   = ws;                                // B*T*256
    float* seqA = xg   + (size_t)B * T * 256;        // B*T*64
    float* seqB = seqA + (size_t)B * T * 64;         // B*T*64
    float* Hc   = seqB + (size_t)B * T * 64;         // B*3*T
    float* bufA = Hc   + (size_t)B * 3 * T;          // B*5*T
    float* bufB = bufA + (size_t)B * 5 * T;          // B*5*T
    float* gate = bufB + (size_t)B * 5 * T;          // B*T
    unsigned* wP = (unsigned*)(gate + (size_t)B * T); // 10*8192 u32

    dim3 pg(B * (T / 16)), pb(256);

    pack_w<<<320, 256, 0, stream>>>(l1Whh, l2Whh, Wih12, l2Wih, wP);

    // ---- LSTM1: proj layer0 + chunked 3-layer scan ----
    proj_kernel<<<pg, pb, 0, stream>>>(data, Wih0, l1b, nullptr, xg, 40, T);
    scan3_kernel<<<2, 192, 0, stream>>>(xg, wP, wP + 6 * 8192, l1b, h01, c01, seqA, T);

    // ---- temporal-attention gate ----
    stats_kernel<<<(2 * T) / 4, 256, 0, stream>>>(seqA, Hc, T);
    middle_kernel<<<1, 1024, 0, stream>>>(Hc, cw1, cb1, cw2, cb2, cw3, cb3, cw4, cb4,
                                          bufA, bufB, gate, T);

    // ---- LSTM2: proj layer0 (gate folded) + chunked 3-layer scan ----
    proj_kernel<<<pg, pb, 0, stream>>>(seqA, l2Wih, l2b, gate, xg, 64, T);
    scan3_kernel<<<2, 192, 0, stream>>>(xg, wP + 3 * 8192, wP + 8 * 8192, l2b, h02, c02, seqB, T);

    // ---- head ----
    final_kernel<<<(2 * T) / 4, 256, 0, stream>>>(seqB, fc1w, fc1b, fc2w, fc2b, out, T);
}

// Round 3
// 8378.280 us; speedup vs baseline: 1.1629x; 1.1629x over previous
//
#include <hip/hip_runtime.h>
#include <hip/hip_bf16.h>
#include <cstdint>
#include <cstddef>

#define DEV __device__ __forceinline__

typedef _Float16 h2v __attribute__((ext_vector_type(2)));
typedef unsigned u4v __attribute__((ext_vector_type(4)));

DEV float sigmoidf_(float x) { return 1.0f / (1.0f + __expf(-x)); }
DEV float tanhf_(float x) {
    float e = __expf(2.0f * x);
    return 1.0f - 2.0f / (e + 1.0f);
}
DEV h2v asH2(unsigned x) { union { unsigned u; h2v h; } c; c.u = x; return c.h; }

// Un-sinkable, un-rematerializable 16B load (resident weights).
DEV u4v gload(const void* p) {
    u4v r;
    asm volatile("global_load_dwordx4 %0, %1, off\n\ts_waitcnt vmcnt(0)"
                 : "=v"(r) : "v"(p) : "memory");
    return r;
}

// LDS-only barrier: does NOT drain vmcnt; global prefetch/stores stay in flight.
#define LDS_BARRIER() asm volatile("s_waitcnt lgkmcnt(0)\n\ts_barrier" ::: "memory")

// ---------------------------------------------------------------------------
// Pack 10 matrices (256x64 each) to f16 pairs, split-K layout:
//   dst[m][half][qs][u][w]   (qs = q*4+s: gate q, slice s; w = word 0..3)
// m: 0-2 l1Whh, 3-5 l2Whh, 6-7 Wih12 (l1 layers 1,2), 8-9 l2Wih layers 1,2.
// Quad (half,q,s,u) holds W[gate q][unit u][k = 32*half + 8*s .. +7].
// ---------------------------------------------------------------------------
__global__ __launch_bounds__(256) void pack_w(
    const float* __restrict__ l1Whh, const float* __restrict__ l2Whh,
    const float* __restrict__ Wih12, const float* __restrict__ l2Wih,
    unsigned* __restrict__ wP)
{
    int idx = blockIdx.x * 256 + threadIdx.x;   // 10*8192 = 81920
    int m = idx >> 13;
    int rem = idx & 8191;
    int half = rem >> 12;
    int qs = (rem >> 8) & 15;
    int u = (rem >> 2) & 63;
    int w = rem & 3;
    int q = qs >> 2, s = qs & 3;
    int jp = 16 * half + 4 * s + w;

    const float* W;
    if (m < 3)      W = l1Whh + (size_t)m * 16384;
    else if (m < 6) W = l2Whh + (size_t)(m - 3) * 16384;
    else if (m < 8) W = Wih12 + (size_t)(m - 6) * 16384;
    else            W = l2Wih + (size_t)(m - 7) * 16384;   // layers 1,2

    const float* row = W + (size_t)(q * 64 + u) * 64;
    union { h2v h; unsigned u32; } c;
    c.h = (h2v){(_Float16)row[2 * jp], (_Float16)row[2 * jp + 1]};
    wP[idx] = c.u32;
}

// ---------------------------------------------------------------------------
// Input projection (layer 0 of each stack only): xg[b,t,u*4+q] unit-major.
// ---------------------------------------------------------------------------
__global__ __launch_bounds__(256) void proj_kernel(
    const float* __restrict__ x, const float* __restrict__ Wih,
    const float* __restrict__ bias, const float* __restrict__ gate,
    float* __restrict__ xg, int D, int T)
{
    __shared__ float xS[16 * 64];
    int tb = T / 16;
    int b  = blockIdx.x / tb;
    int t0 = (blockIdx.x % tb) * 16;
    int tid = threadIdx.x;

    int n = 16 * D;
    for (int e = tid; e < n; e += 256) {
        int t = e / D;
        int i = e - t * D;
        float v = x[((size_t)(b * T + t0 + t)) * D + i];
        if (gate) v += gate[b * T + t0 + t];
        xS[t * D + i] = v;
    }
    __syncthreads();

    int g = tid;
    float acc[16];
    float bg = bias[g];
#pragma unroll
    for (int t = 0; t < 16; t++) acc[t] = bg;

    const float* wr = Wih + (size_t)g * D;
    for (int i = 0; i < D; i++) {
        float w = wr[i];
#pragma unroll
        for (int t = 0; t < 16; t++) acc[t] += xS[t * D + i] * w;
    }

    float* og = xg + ((size_t)(b * T + t0)) * 256 + (g & 63) * 4 + (g >> 6);
#pragma unroll
    for (int t = 0; t < 16; t++) og[(size_t)t * 256] = acc[t];
}

// ---------------------------------------------------------------------------
// Chunked 3-layer LSTM scan v18: ONE block per batch, THREE waves (1/layer).
//
// v17 post-mortem: per-tick per-lane LDS weight streaming = ~1800 cy/tick of
// shared LDS pipe (ds_read_b128 ~12cy, m134) -> the regression. v18 keeps
// Whh RESIDENT (128 VGPR/wave; 3-wave grant measured 188) and batches the
// Wih.h_below work per chunk so each Wih quad is read from LDS once per 4
// ticks instead of once per tick:
//  * Epochs of RR=8 ticks, 1 barrier each. Wave l handles chunk m=e-l.
//  * Epoch body (l>0): GEMMHALF(0) -> scan ticks 0..3 -> GEMMHALF(1) ->
//    scan 4..7. GEMMHALF: j-outer over 8 k-slices; per slice: 4 broadcast
//    h-row reads + 4 per-lane Wih quad reads + 64 fdot2 into acc4[4]
//    (float4 = 4 gates; bias folded into init).
//  * acc4[] double-duty: L0 uses it as the 4-deep rolling x prefetch
//    buffer (saves 16 VGPRs of static demand -> fits the 188 grant).
//  * h exchange: hself (same-wave broadcast round trip), hchunk
//    (epoch-parity double buffer, cross-wave, barrier-published).
// ---------------------------------------------------------------------------
#define RR 8

__global__
__attribute__((amdgpu_flat_work_group_size(192, 192), amdgpu_waves_per_eu(1, 1)))
void scan3_kernel(
    const float* __restrict__ xg, const unsigned* __restrict__ whhP,
    const unsigned* __restrict__ wihP, const float* __restrict__ bvec,
    const float* __restrict__ h0, const float* __restrict__ c0,
    float* __restrict__ Hout, int T)
{
    __shared__ __align__(16) u4v wihS[4096];                 // 64 KB (Wih l1,l2)
    __shared__ __align__(16) _Float16 hchunk[2][2][RR][64];  // 4 KB
    __shared__ __align__(16) _Float16 hself[3][64];

    const int b = blockIdx.x, tid = threadIdx.x;
    const int l = tid >> 6, u = tid & 63;

    // stage Wih (both layers, packed layout) into LDS
    for (int i = tid; i < 4096; i += 192) wihS[i] = ((const u4v*)wihP)[i];

    // resident Whh: whh[g*8+ks] = W[gate g][unit u][k=8*ks..8*ks+7]
    u4v whh[32];
    {
        const u4v* wp = (const u4v*)whhP + (size_t)l * 2048 + u;
#pragma unroll
        for (int g = 0; g < 4; g++)
#pragma unroll
            for (int ks = 0; ks < 8; ks++)
                whh[g * 8 + ks] = gload(wp + (ks >> 2) * 1024 + (g * 4 + (ks & 3)) * 64);
    }

    float cst = c0[l * 128 + b * 64 + u];
    hself[l][u] = (_Float16)h0[l * 128 + b * 64 + u];
    float4 bl = make_float4(0.f, 0.f, 0.f, 0.f);
    if (l > 0) {
        const float* bb = bvec + l * 256;
        bl = make_float4(bb[u], bb[64 + u], bb[128 + u], bb[192 + u]);
    }

    // acc4: L0 = rolling x prefetch (ticks tau..tau+3); L1/L2 = GEMM accums
    const float4* xp = (const float4*)(xg + (size_t)b * T * 256) + u;
    float4 acc4[4];
    if (l == 0) {
#pragma unroll
        for (int k = 0; k < 4; k++) acc4[k] = xp[(size_t)k * 64];
    } else {
#pragma unroll
        for (int k = 0; k < 4; k++) acc4[k] = bl;
    }

    float* houtp = Hout + (size_t)b * T * 64 + u;
    const u4v* hs = (const u4v*)&hself[l][0];
    const u4v* wb = wihS + (size_t)(l > 0 ? l - 1 : 0) * 2048 + u;
    const int lb = (l > 0 ? l - 1 : 0);

    __syncthreads();

#define FD(HP, WV, A) A = __builtin_amdgcn_fdot2(asH2(HP), asH2(WV), A, false)
#define FD4(HQ, WQ, A) { FD(HQ.x, (WQ).x, A); FD(HQ.y, (WQ).y, A); \
                         FD(HQ.z, (WQ).z, A); FD(HQ.w, (WQ).w, A); }

    // one gate of the chunk-GEMM: stream Wih quad once, hit 4 ticks
#define GEMMG(G, ACCSEL) {                                              \
    u4v wq = wb[(ks >> 2) * 1024 + ((G) * 4 + (ks & 3)) * 64];          \
    FD4(hb0, wq, acc4[0].ACCSEL);                                       \
    FD4(hb1, wq, acc4[1].ACCSEL);                                       \
    FD4(hb2, wq, acc4[2].ACCSEL);                                       \
    FD4(hb3, wq, acc4[3].ACCSEL);                                       \
}

#define GEMMHALF(H) {                                                   \
    acc4[0] = bl; acc4[1] = bl; acc4[2] = bl; acc4[3] = bl;             \
    _Pragma("unroll")                                                   \
    for (int ks = 0; ks < 8; ks++) {                                    \
        u4v hb0 = hbase[((H) * 4 + 0) * 8 + ks];                        \
        u4v hb1 = hbase[((H) * 4 + 1) * 8 + ks];                        \
        u4v hb2 = hbase[((H) * 4 + 2) * 8 + ks];                        \
        u4v hb3 = hbase[((H) * 4 + 3) * 8 + ks];                        \
        GEMMG(0, x) GEMMG(1, y) GEMMG(2, z) GEMMG(3, w)                 \
    }                                                                   \
}

    // one LSTM tick: Whh dots from resident regs, h via broadcast reads
#define SCANTICK(R, XV, TAU) {                                          \
    float4 xv_ = (XV);                                                  \
    float aI = xv_.x, aF = xv_.y, aG = xv_.z, aO = xv_.w;               \
    _Pragma("unroll")                                                   \
    for (int s = 0; s < 8; s++) {                                       \
        u4v hq = hs[s];                                                 \
        FD4(hq, whh[0 + s],  aI);                                       \
        FD4(hq, whh[8 + s],  aF);                                       \
        FD4(hq, whh[16 + s], aG);                                       \
        FD4(hq, whh[24 + s], aO);                                       \
    }                                                                   \
    cst = sigmoidf_(aF) * cst + sigmoidf_(aI) * tanhf_(aG);             \
    float hv = sigmoidf_(aO) * tanhf_(cst);                             \
    hself[l][u] = (_Float16)hv;                                         \
    if (l < 2) hpub[(R) * 64 + u] = (_Float16)hv;                       \
    else       houtp[(size_t)(TAU) * 64] = hv;                          \
}

    const int NC = T / RR;
    for (int e = 0; e < NC + 2; e++) {
        int m = e - l;
        if (m >= 0 && m < NC) {
            const int p = m & 1;
            const int base = m * RR;
            _Float16* hpub = &hchunk[l < 2 ? l : 0][p][0][0];
            if (l == 0) {
#pragma unroll
                for (int r = 0; r < RR; r++) {
                    int tau = base + r;
                    float4 xv = acc4[r & 3];
                    int tp = tau + 4; if (tp > T - 1) tp = T - 1;
                    acc4[r & 3] = xp[(size_t)tp * 64];
                    SCANTICK(r, xv, tau)
                }
            } else {
                const u4v* hbase = (const u4v*)&hchunk[lb][p][0][0];
                GEMMHALF(0)
                SCANTICK(0, acc4[0], base + 0)
                SCANTICK(1, acc4[1], base + 1)
                SCANTICK(2, acc4[2], base + 2)
                SCANTICK(3, acc4[3], base + 3)
                GEMMHALF(1)
                SCANTICK(4, acc4[0], base + 4)
                SCANTICK(5, acc4[1], base + 5)
                SCANTICK(6, acc4[2], base + 6)
                SCANTICK(7, acc4[3], base + 7)
            }
        }
        LDS_BARRIER();   // publish hchunk writes; epoch parity flip
    }
#undef FD
#undef FD4
#undef GEMMG
#undef GEMMHALF
#undef SCANTICK
}

// ---------------------------------------------------------------------------
// Hc[b, {max,mean,std(ddof=1)}, t] over hidden dim (64). One wave per (b,t).
// ---------------------------------------------------------------------------
__global__ __launch_bounds__(256) void stats_kernel(
    const float* __restrict__ H, float* __restrict__ Hc, int T)
{
    int wid = threadIdx.x >> 6, lane = threadIdx.x & 63;
    int bt = blockIdx.x * 4 + wid;
    int b = bt / T, t = bt - b * T;

    float x = H[(size_t)bt * 64 + lane];
    float mx = x, sm = x;
#pragma unroll
    for (int m = 32; m >= 1; m >>= 1) {
        mx = fmaxf(mx, __shfl_xor(mx, m));
        sm += __shfl_xor(sm, m);
    }
    float mean = sm * (1.0f / 64.0f);
    float d = x - mean;
    float ss = d * d;
#pragma unroll
    for (int m = 32; m >= 1; m >>= 1) ss += __shfl_xor(ss, m);
    float sd = sqrtf(ss * (1.0f / 63.0f));

    if (lane == 0) {
        float* o = Hc + (size_t)b * 3 * T;
        o[0 * T + t] = mx;
        o[1 * T + t] = mean;
        o[2 * T + t] = sd;
    }
}

// ---------------------------------------------------------------------------
// Middle conv/BN chain, single workgroup (1024 threads).
// ---------------------------------------------------------------------------
template <int CIN, int COUT, int MODE>
DEV void conv_bn_stage(const float* __restrict__ in, const float* __restrict__ w,
                       const float* __restrict__ bias, float* __restrict__ out,
                       float* __restrict__ gate, int T, int tid,
                       float* rs, float* rq, float* stm, float* sti)
{
    float lsum[COUT], lss[COUT];
#pragma unroll
    for (int oc = 0; oc < COUT; oc++) { lsum[oc] = 0.f; lss[oc] = 0.f; }

    for (int k = 0; k < 8; k++) {
        int p = tid + k * 1024;
        int b = p / T;
        int t = p - b * T;
        float acc[COUT];
#pragma unroll
        for (int oc = 0; oc < COUT; oc++) acc[oc] = bias[oc];
#pragma unroll
        for (int ic = 0; ic < CIN; ic++) {
            const float* row = in + ((size_t)b * CIN + ic) * T;
            float xv[11];
#pragma unroll
            for (int kk = 0; kk < 11; kk++) {
                int tt = t + kk - 5;
                xv[kk] = (tt >= 0 && tt < T) ? row[tt] : 0.f;
            }
#pragma unroll
            for (int oc = 0; oc < COUT; oc++) {
                const float* wr = w + ((size_t)oc * CIN + ic) * 11;
#pragma unroll
                for (int kk = 0; kk < 11; kk++) acc[oc] += xv[kk] * wr[kk];
            }
        }
#pragma unroll
        for (int oc = 0; oc < COUT; oc++) {
            out[((size_t)b * COUT + oc) * T + t] = acc[oc];
            lsum[oc] += acc[oc];
            lss[oc] += acc[oc] * acc[oc];
        }
    }
    __syncthreads();

    int lane = tid & 63, wid = tid >> 6;
#pragma unroll
    for (int oc = 0; oc < COUT; oc++) {
        float s = lsum[oc], qq = lss[oc];
#pragma unroll
        for (int m = 32; m >= 1; m >>= 1) {
            s += __shfl_xor(s, m);
            qq += __shfl_xor(qq, m);
        }
        if (lane == 0) { rs[wid] = s; rq[wid] = qq; }
        __syncthreads();
        if (tid == 0) {
            float S = 0.f, Q = 0.f;
            for (int i = 0; i < 16; i++) { S += rs[i]; Q += rq[i]; }
            float m_ = S / (float)(2 * T);
            float v = Q / (float)(2 * T) - m_ * m_;
            stm[oc] = m_;
            sti[oc] = rsqrtf(v + 1e-5f);
        }
        __syncthreads();
    }

    for (int k = 0; k < 8; k++) {
        int p = tid + k * 1024;
        int b = p / T;
        int t = p - b * T;
#pragma unroll
        for (int oc = 0; oc < COUT; oc++) {
            size_t idx = ((size_t)b * COUT + oc) * T + t;
            float v = (out[idx] - stm[oc]) * sti[oc];
            if (MODE == 0) out[idx] = fmaxf(v, 0.f);
            else           gate[p] = sigmoidf_(v);
        }
    }
    __syncthreads();
}

__global__ __launch_bounds__(1024) void middle_kernel(
    const float* __restrict__ Hc,
    const float* __restrict__ w1, const float* __restrict__ b1,
    const float* __restrict__ w2, const float* __restrict__ b2,
    const float* __restrict__ w3, const float* __restrict__ b3,
    const float* __restrict__ w4, const float* __restrict__ b4,
    float* __restrict__ bufA, float* __restrict__ bufB,
    float* __restrict__ gate, int T)
{
    __shared__ float rs[16], rq[16], stm[8], sti[8];
    int tid = threadIdx.x;
    conv_bn_stage<3, 3, 0>(Hc,   w1, b1, bufA, nullptr, T, tid, rs, rq, stm, sti);
    conv_bn_stage<3, 5, 0>(bufA, w2, b2, bufB, nullptr, T, tid, rs, rq, stm, sti);
    conv_bn_stage<5, 5, 0>(bufB, w3, b3, bufA, nullptr, T, tid, rs, rq, stm, sti);
    conv_bn_stage<5, 1, 1>(bufA, w4, b4, bufB, gate,    T, tid, rs, rq, stm, sti);
}

// ---------------------------------------------------------------------------
// Head: y = sigmoid(fc2(fc1(out2))). One wave per (b,t).
// ---------------------------------------------------------------------------
__global__ __launch_bounds__(256) void final_kernel(
    const float* __restrict__ out2, const float* __restrict__ fc1w,
    const float* __restrict__ fc1b, const float* __restrict__ fc2w,
    const float* __restrict__ fc2b, float* __restrict__ out, int T)
{
    int wid = threadIdx.x >> 6, lane = threadIdx.x & 63;
    int bt = blockIdx.x * 4 + wid;

    const float* o2 = out2 + (size_t)bt * 64;
    float acc = fc1b[lane];
    const float* wr = fc1w + (size_t)lane * 64;
#pragma unroll
    for (int k = 0; k < 64; k++) acc += o2[k] * wr[k];

    float p = acc * fc2w[lane];
#pragma unroll
    for (int m = 32; m >= 1; m >>= 1) p += __shfl_xor(p, m);

    if (lane == 0) out[bt] = sigmoidf_(p + fc2b[0]);
}

// ---------------------------------------------------------------------------
extern "C" void kernel_launch(void* const* d_in, const int* in_sizes, int n_in,
                              void* d_out, int out_size, void* d_ws, size_t ws_size,
                              hipStream_t stream)
{
    const float* data  = (const float*)d_in[0];
    const float* h01   = (const float*)d_in[1];
    const float* c01   = (const float*)d_in[2];
    const float* h02   = (const float*)d_in[3];
    const float* c02   = (const float*)d_in[4];
    const float* Wih0  = (const float*)d_in[5];
    const float* Wih12 = (const float*)d_in[6];
    const float* l1Whh = (const float*)d_in[7];
    const float* l1b   = (const float*)d_in[8];
    const float* l2Wih = (const float*)d_in[9];
    const float* l2Whh = (const float*)d_in[10];
    const float* l2b   = (const float*)d_in[11];
    const float* cw1 = (const float*)d_in[12]; const float* cb1 = (const float*)d_in[13];
    const float* cw2 = (const float*)d_in[14]; const float* cb2 = (const float*)d_in[15];
    const float* cw3 = (const float*)d_in[16]; const float* cb3 = (const float*)d_in[17];
    const float* cw4 = (const float*)d_in[18]; const float* cb4 = (const float*)d_in[19];
    const float* fc1w = (const float*)d_in[20]; const float* fc1b = (const float*)d_in[21];
    const float* fc2w = (const float*)d_in[22]; const float* fc2b = (const float*)d_in[23];
    float* out = (float*)d_out;

    const int T = in_sizes[0] / (2 * 40);   // 4096
    const int B = 2;

    float* ws   = (float*)d_ws;
    float* xg   = ws;                                // B*T*256
    float* seqA = xg   + (size_t)B * T * 256;        // B*T*64
    float* seqB = seqA + (size_t)B * T * 64;         // B*T*64
    float* Hc   = seqB + (size_t)B * T * 64;         // B*3*T
    float* bufA = Hc   + (size_t)B * 3 * T;          // B*5*T
    float* bufB = bufA + (size_t)B * 5 * T;          // B*5*T
    float* gate = bufB + (size_t)B * 5 * T;          // B*T
    unsigned* wP = (unsigned*)(gate + (size_t)B * T); // 10*8192 u32

    dim3 pg(B * (T / 16)), pb(256);

    pack_w<<<320, 256, 0, stream>>>(l1Whh, l2Whh, Wih12, l2Wih, wP);

    // ---- LSTM1: proj layer0 + chunked 3-layer scan ----
    proj_kernel<<<pg, pb, 0, stream>>>(data, Wih0, l1b, nullptr, xg, 40, T);
    scan3_kernel<<<2, 192, 0, stream>>>(xg, wP, wP + 6 * 8192, l1b, h01, c01, seqA, T);

    // ---- temporal-attention gate ----
    stats_kernel<<<(2 * T) / 4, 256, 0, stream>>>(seqA, Hc, T);
    middle_kernel<<<1, 1024, 0, stream>>>(Hc, cw1, cb1, cw2, cb2, cw3, cb3, cw4, cb4,
                                          bufA, bufB, gate, T);

    // ---- LSTM2: proj layer0 (gate folded) + chunked 3-layer scan ----
    proj_kernel<<<pg, pb, 0, stream>>>(seqA, l2Wih, l2b, gate, xg, 64, T);
    scan3_kernel<<<2, 192, 0, stream>>>(xg, wP + 3 * 8192, wP + 8 * 8192, l2b, h02, c02, seqB, T);

    // ---- head ----
    final_kernel<<<(2 * T) / 4, 256, 0, stream>>>(seqB, fc1w, fc1b, fc2w, fc2b, out, T);
}